// Round 10
// baseline (315.237 us; speedup 1.0000x reference)
//
#include <hip/hip_runtime.h>
#include <hip/hip_bf16.h>
#include <stdint.h>

// ---------------------------------------------------------------------------
// EfficientCrossAttention on MI355X (gfx950), bf16 MFMA pipeline.
// prep (cast+transpose) -> fused Q/KV projection GEMM -> flash attention
// (S^T trick; 32q x 32key per wave, all full-rate K=32 MFMA) -> Oproj GEMM.
// History: R8 full-rate PV (104.7->84.8us); R10 Vt key-permute (->80.8us);
// R11 PV-deferral REGRESSED; R12 V-from-global 4KB-stride REGRESSED;
// R13 Vfrag coalesced (82.8us NEUTRAL); R14 barrier-free K rings (86.6us);
// R15 vf-first vmcnt order (86.2us NEUTRAL — K-drain theory refuted).
// R17 model: across all configs MfmaUtil+VALUBusy ~ 85-95% and dur = SUM of
// pipe demands (MFMA ~90k cy/SIMD, VALU ~95k: 32 quarter-rate exp2 + cvt).
// Pipes are separate HW (m114) -> floor should be max(90,95)k ~ 40us; we
// run at the sum because waves are PHASE-LOCKED: same start, same code ->
// all resident waves do exp together (VALU bursts, matrix idle) then MFMA
// together. R17: desync — (1) one-time start stagger 0/384/768/1152cy keyed
// on (block-hash + w)&3 (hash desyncs co-resident blocks if same-w waves
// share a SIMD); (2) s_setprio(1) around the MFMA cluster so anti-phase is
// self-stabilizing. lsum moved after both exps to form one MFMA cluster.
// Discriminator: sum>110% + dur<70us confirms; flat refutes (then the
// issue-port floor ~77us is the roofline and R10 is the keeper).
// d_ws layout:
//   WqT @0MB  WkvT @2MB  WoT @6MB  qb @8MB  kvb @24MB
//   Qp (B*H,2048,64) @40MB   Kb (B*H,2048,64) @56MB
//   Vfrag (16MB) @72MB       Ob (8192x1024)   @88MB
// ---------------------------------------------------------------------------

typedef __bf16 bf16_t;
typedef __bf16 bf16x8 __attribute__((ext_vector_type(8)));
typedef __bf16 bf16x4 __attribute__((ext_vector_type(4)));
typedef short  s16x4  __attribute__((ext_vector_type(4)));
typedef float  f32x4  __attribute__((ext_vector_type(4)));

#define MFMA16x32(a, b, c) __builtin_amdgcn_mfma_f32_16x16x32_bf16((a), (b), (c), 0, 0, 0)

__device__ __forceinline__ float fast_exp2(float x) {
#if __has_builtin(__builtin_amdgcn_exp2f)
    return __builtin_amdgcn_exp2f(x);
#else
    return exp2f(x);
#endif
}

// async global->LDS, 16B/lane; LDS dest = wave-uniform base + lane*16
__device__ __forceinline__ void gload16(const void* g, const void* l) {
    __builtin_amdgcn_global_load_lds(
        (__attribute__((address_space(1))) void*)(uintptr_t)g,
        (__attribute__((address_space(3))) void*)(uintptr_t)l,
        16, 0, 0);
}

// log2(e)/sqrt(HD=64), folded into the Q projection epilogue
#define ATTN_SCALE 0.18033688011112042f

// ---------------------------------------------------------------------------
// merged prep: fp32->bf16 casts (blocks 0..8191) + 3 weight transposes
__global__ void prep_kernel(const float* __restrict__ q, const float* __restrict__ kv,
                            const float* __restrict__ Wq, const float* __restrict__ Wkv,
                            const float* __restrict__ Wo, bf16_t* __restrict__ qb,
                            bf16_t* __restrict__ kvb, bf16_t* __restrict__ WqT,
                            bf16_t* __restrict__ WkvT, bf16_t* __restrict__ WoT) {
    __shared__ float tile[64][65];
    int bid = blockIdx.x;
    const int t = threadIdx.x;
    if (bid < 8192) {
        const float* in;
        bf16_t* out;
        if (bid < 4096) { in = q; out = qb; }
        else            { in = kv; out = kvb; bid -= 4096; }
        int i = (bid * 256 + t) * 8;
        const float4* p = (const float4*)(in + i);
        float4 x = p[0], y = p[1];
        bf16x8 v;
        v[0] = (bf16_t)x.x; v[1] = (bf16_t)x.y; v[2] = (bf16_t)x.z; v[3] = (bf16_t)x.w;
        v[4] = (bf16_t)y.x; v[5] = (bf16_t)y.y; v[6] = (bf16_t)y.z; v[7] = (bf16_t)y.w;
        *(bf16x8*)(out + i) = v;
        return;
    }
    bid -= 8192;
    int z = bid >> 9, rem = bid & 511;
    int xb = rem & 31, yb = rem >> 5;
    const float* W;
    bf16_t* WT;
    int N;
    if (z == 0)      { W = Wq;  WT = WqT;  N = 1024; }
    else if (z == 1) { W = Wkv; WT = WkvT; N = 2048; }
    else             { W = Wo;  WT = WoT;  N = 1024; }
    if (xb * 64 >= N) return;
    const int K = 1024;
    const int n0 = xb * 64, k0 = yb * 64;
#pragma unroll
    for (int i = 0; i < 16; ++i) {
        int idx = i * 256 + t;
        int r = idx >> 6, c = idx & 63;
        tile[r][c] = W[(size_t)(k0 + r) * N + n0 + c];
    }
    __syncthreads();
#pragma unroll
    for (int i = 0; i < 16; ++i) {
        int idx = i * 256 + t;
        int r = idx >> 6, c = idx & 63;
        WT[(size_t)(n0 + r) * K + k0 + c] = (bf16_t)tile[c][r];
    }
}

// ---------------------------------------------------------------------------
// Fused Q + KV projection GEMM (one launch, 24x64 = 1536 blocks).
// blockIdx.x < 8: Qproj (scaled, -> Qp); else KVproj (-> Kb / Vfrag).
// 128x128 tiles, m97 staging, 2-bit XOR chunk swizzle.
// V epilogue writes attn-fragment order directly from accumulators:
// Vfrag element offset = (((bh*32+t)*2+wk)*4+nh)*512 + lane*8 + e, where
// e<4 -> key wk*32+quad*4+e (acc[2wk][n]), e>=4 -> key wk*32+16+quad*4+(e-4)
// (acc[2wk+1][n]). Each (wk,nh) block is 1KB, lane-contiguous.
__global__ __launch_bounds__(256, 3)
void gemm_qkv(const bf16_t* __restrict__ qb, const bf16_t* __restrict__ kvb,
              const bf16_t* __restrict__ WqT, const bf16_t* __restrict__ WkvT,
              const float* __restrict__ bq, const float* __restrict__ bkv,
              bf16_t* __restrict__ Qp, bf16_t* __restrict__ Kb,
              bf16_t* __restrict__ Vt) {
    __shared__ __align__(16) char pool[16384];
    bf16_t* sA = (bf16_t*)pool;
    bf16_t* sB = (bf16_t*)(pool + 8192);

    const int tid  = threadIdx.x;
    const int lane = tid & 63, w = tid >> 6;
    const int wr = w >> 1, wc = w & 1;
    const int quad = lane >> 4, l15 = lane & 15;
    const int x3 = l15 & 3;
    const bool isQ = blockIdx.x < 8;
    const bf16_t* A    = isQ ? qb : kvb;
    const bf16_t* BT   = isQ ? WqT : WkvT;
    const float*  bias = isQ ? bq : bkv;
    const int row0 = blockIdx.y * 128;
    const int col0 = (isQ ? blockIdx.x : (blockIdx.x - 8)) * 128;
    const int K = 1024;

    f32x4 acc[4][4];
    const f32x4 fz = {0.f, 0.f, 0.f, 0.f};
#pragma unroll
    for (int m = 0; m < 4; ++m)
#pragma unroll
        for (int n = 0; n < 4; ++n) acc[m][n] = fz;

    for (int kt = 0; kt < K; kt += 32) {
#pragma unroll
        for (int i = 0; i < 2; ++i) {
            int c = i * 256 + tid;
            int r = c >> 2, cr = c & 3;
            int g = cr ^ (r & 3);
            gload16(A + (size_t)(row0 + r) * K + kt + g * 8,
                    (const char*)sA + i * 4096 + w * 1024);
            gload16(BT + (size_t)(col0 + r) * K + kt + g * 8,
                    (const char*)sB + i * 4096 + w * 1024);
        }
        __syncthreads();

        bf16x8 af[4], bfr[4];
#pragma unroll
        for (int m = 0; m < 4; ++m)
            af[m] = *(const bf16x8*)(sA + (wr * 64 + m * 16 + l15) * 32 + (quad ^ x3) * 8);
#pragma unroll
        for (int n = 0; n < 4; ++n)
            bfr[n] = *(const bf16x8*)(sB + (wc * 64 + n * 16 + l15) * 32 + (quad ^ x3) * 8);
#pragma unroll
        for (int m = 0; m < 4; ++m)
#pragma unroll
            for (int n = 0; n < 4; ++n)
                acc[m][n] = MFMA16x32(af[m], bfr[n], acc[m][n]);
        __syncthreads();
    }

    if (!isQ && col0 >= 1024) {
        // pure-V block: write Vfrag directly from accumulators (coalesced
        // 16B/lane stores, 1KB per (wk,nh) block). No LDS transpose.
        const int j0  = col0 - 1024 + wc * 64;   // V column base = head h*64
        const int hh  = j0 >> 6;                 // head index
        const int sk0 = row0 + wr * 64;          // key base (one 64-key tile)
        const int bb  = sk0 >> 11;               // batch
        const int tt  = (sk0 & 2047) >> 6;       // key tile within batch-head
        bf16_t* vdst = Vt + ((((size_t)(bb * 16 + hh) * 32 + tt) * 2) * 4) * 512 +
                       (size_t)lane * 8;
#pragma unroll
        for (int wkh = 0; wkh < 2; ++wkh)
#pragma unroll
            for (int n = 0; n < 4; ++n) {
                float bv = bkv[1024 + j0 + n * 16 + l15];
                bf16x8 v8;
#pragma unroll
                for (int r = 0; r < 4; ++r) {
                    v8[r]     = (bf16_t)(acc[2 * wkh][n][r] + bv);
                    v8[4 + r] = (bf16_t)(acc[2 * wkh + 1][n][r] + bv);
                }
                *(bf16x8*)(vdst + ((size_t)wkh * 4 + n) * 512) = v8;
            }
        return;
    }

#pragma unroll
    for (int m = 0; m < 4; ++m) {
        int rg_base = row0 + wr * 64 + m * 16 + quad * 4;
#pragma unroll
        for (int n = 0; n < 4; ++n) {
            int cg = col0 + wc * 64 + n * 16 + l15;
            float bv = bias[cg];
#pragma unroll
            for (int r = 0; r < 4; ++r) {
                int rg = rg_base + r;
                float v = acc[m][n][r] + bv;
                int bb = rg >> 11, sr = rg & 2047;
                int hh = cg >> 6, hd = cg & 63;
                size_t idx = (((size_t)(bb * 16 + hh) * 2048 + sr) << 6) | hd;
                if (isQ) Qp[idx] = (bf16_t)(v * ATTN_SCALE);
                else     Kb[idx] = (bf16_t)v;
            }
        }
    }
}

// ---------------------------------------------------------------------------
// Oproj GEMM: C = A(MxK) * BT(NxK)^T + bias, fp32 row-major out.
__global__ __launch_bounds__(256, 3)
void gemm_out(const bf16_t* __restrict__ A, const bf16_t* __restrict__ BT,
              const float* __restrict__ bias, float* __restrict__ out,
              int M, int N, int K) {
    __shared__ __align__(16) bf16_t sA[128 * 32];
    __shared__ __align__(16) bf16_t sB[128 * 32];
    const int tid  = threadIdx.x;
    const int lane = tid & 63, w = tid >> 6;
    const int wr = w >> 1, wc = w & 1;
    const int quad = lane >> 4, l15 = lane & 15;
    const int x3 = l15 & 3;
    const int row0 = blockIdx.y * 128, col0 = blockIdx.x * 128;

    f32x4 acc[4][4];
    const f32x4 fz = {0.f, 0.f, 0.f, 0.f};
#pragma unroll
    for (int m = 0; m < 4; ++m)
#pragma unroll
        for (int n = 0; n < 4; ++n) acc[m][n] = fz;

    for (int kt = 0; kt < K; kt += 32) {
#pragma unroll
        for (int i = 0; i < 2; ++i) {
            int c = i * 256 + tid;
            int r = c >> 2, cr = c & 3;
            int g = cr ^ (r & 3);
            gload16(A + (size_t)(row0 + r) * K + kt + g * 8,
                    (const char*)sA + i * 4096 + w * 1024);
            gload16(BT + (size_t)(col0 + r) * K + kt + g * 8,
                    (const char*)sB + i * 4096 + w * 1024);
        }
        __syncthreads();

        bf16x8 af[4], bfr[4];
#pragma unroll
        for (int m = 0; m < 4; ++m)
            af[m] = *(const bf16x8*)(sA + (wr * 64 + m * 16 + l15) * 32 + (quad ^ x3) * 8);
#pragma unroll
        for (int n = 0; n < 4; ++n)
            bfr[n] = *(const bf16x8*)(sB + (wc * 64 + n * 16 + l15) * 32 + (quad ^ x3) * 8);
#pragma unroll
        for (int m = 0; m < 4; ++m)
#pragma unroll
            for (int n = 0; n < 4; ++n)
                acc[m][n] = MFMA16x32(af[m], bfr[n], acc[m][n]);
        __syncthreads();
    }

#pragma unroll
    for (int m = 0; m < 4; ++m) {
        int rg_base = row0 + wr * 64 + m * 16 + quad * 4;
#pragma unroll
        for (int n = 0; n < 4; ++n) {
            int cg = col0 + wc * 64 + n * 16 + l15;
            float bv = bias[cg];
#pragma unroll
            for (int r = 0; r < 4; ++r)
                out[(size_t)(rg_base + r) * N + cg] = acc[m][n][r] + bv;
        }
    }
}

// ---------------------------------------------------------------------------
// Flash attention. 1-D grid of 2048 blocks, bh-major: bh = id&63, qt = id>>6.
// Wave w = (wq = w>>1 q-half, wk = w&1 key-half): 32 q-rows x 32 keys per
// wave, all MFMAs full-rate 16x16x32. In-tile order: QK -> exp -> MFMA
// cluster (lsum+PV).
// R15 base (barrier-free, per-wave private K ring, V from Vfrag, vf-first
// issue order) + R17 phase-desync:
//  (1) start stagger 0/~384/~768/~1152cy by (block-hash + w)&3 — creates
//      anti-phase so one wave's exp (VALU) overlaps another's MFMA;
//  (2) s_setprio(1) around the MFMA cluster — a wave in its MFMA phase
//      preempts issue, making anti-phase self-stabilizing.
// Pool 40960B: sQ@0 (8KB, persistent), rings@8192 (4x8KB) -> 4 blocks/CU.
// Epilogue: one barrier to drain all waves (rings overlay redO/redL),
// then redL write, then the 2-phase redO reduction.
// __launch_bounds__(256,4); spill tripwire: WRITE_SIZE ~17.3k.
__global__ __launch_bounds__(256, 4)
void attn_kernel(const bf16_t* __restrict__ Qp, const bf16_t* __restrict__ Kb,
                 const bf16_t* __restrict__ Vt, bf16_t* __restrict__ Ob) {
    __shared__ __align__(16) char pool[40960];
    bf16_t* sQ   = (bf16_t*)pool;
    float*  redO = (float*)pool;               // [4][32][32] (end phase)
    float*  redL = (float*)(pool + 16384);     // [4][32]   (end phase)

    const int tid = threadIdx.x;
    const int lane = tid & 63, w = tid >> 6;
    const int wq = w >> 1, wk = w & 1;
    const int quad = lane >> 4, l15 = lane & 15;
    const int x7 = l15 & 7;
    const int bhid = blockIdx.x & 63;
    const int qt   = blockIdx.x >> 6;
    const int b = bhid >> 4, h = bhid & 15;
    const size_t bh = (size_t)bhid;

    const bf16_t* Qg = Qp + bh * (2048 * 64) + (size_t)qt * (64 * 64);
    const bf16_t* Kg = Kb + bh * (2048 * 64);
    // Vfrag: element = bh*131072 + t*4096 + wk*2048 + nh*512 + lane*8 + e
    const bf16_t* vtile = Vt + bh * 131072 + (size_t)wk * 2048 + (size_t)lane * 8;

    // Q staging map (block-cooperative)
    const int srow = tid >> 3;
    const int sg   = (tid & 7) ^ (srow & 7);

    // K private-ring staging map: wave stages rows wk*32 + j*8 + (lane>>3),
    // slot lane&7 <- global chunk (lane&7)^(lane>>3)
    const bf16_t* Kw = Kg + wk * 2048;           // our 32-key half, tile 0
    const int krl = lane >> 3;
    const size_t klo = (size_t)krl * 64 + (size_t)(((lane & 7) ^ krl)) * 8;
    char* kring = pool + 8192 + w * 8192;

    // stage Q (cooperative) + K(0) (private)
#pragma unroll
    for (int hh = 0; hh < 2; ++hh) {
        int row = hh * 32 + srow;
        gload16(Qg + (size_t)row * 64 + sg * 8, pool + hh * 4096 + w * 1024);
    }
#pragma unroll
    for (int j = 0; j < 4; ++j)
        gload16(Kw + (size_t)j * 512 + klo, kring + j * 1024);
    __syncthreads();   // sQ fully staged (also drains our K(0) gload16s)

    // Q B-frags: our 32 q-rows, both hd halves (sQ persists all loop)
    bf16x8 qf[2][2];
#pragma unroll
    for (int qb = 0; qb < 2; ++qb)
#pragma unroll
        for (int hh = 0; hh < 2; ++hh)
            qf[qb][hh] = *(const bf16x8*)(sQ + (wq * 32 + qb * 16 + l15) * 64 +
                                          ((hh * 4 + quad) ^ x7) * 8);

    // phase stagger: desync waves so one wave's exp overlaps another's MFMA.
    // Hash the block id so co-resident blocks desync even if same-w waves
    // share a SIMD. Cost <= ~1152cy once; loop is ~26k cy.
    {
        unsigned ph = ((unsigned)blockIdx.x * 2654435761u) >> 28;
        unsigned d  = (ph + (unsigned)w) & 3u;
        if (d & 1u) __builtin_amdgcn_s_sleep(6);    // ~384 cy
        if (d & 2u) __builtin_amdgcn_s_sleep(12);   // ~768 cy
    }

    const f32x4 fz = {0.f, 0.f, 0.f, 0.f};
    bf16x8 ones8;
#pragma unroll
    for (int i = 0; i < 8; ++i) ones8[i] = (bf16_t)1.f;

    f32x4 o_[2][4];   // [qb][nh]: O[wq*32+qb*16+quad*4+r][nh*16+l15], partial over our keys
    f32x4 lacc[2];    // [qb]: row-sum partials
#pragma unroll
    for (int qb = 0; qb < 2; ++qb) {
        lacc[qb] = fz;
#pragma unroll
        for (int nh = 0; nh < 4; ++nh) o_[qb][nh] = fz;
    }

    for (int t = 0; t < 32; ++t) {
        // K(t) ring ready: only its 4 stages can be outstanding here
        asm volatile("s_waitcnt vmcnt(0)" ::: "memory");

        // V(t) FIRST (coalesced 16B/lane): with in-order vmcnt retirement,
        // PV's wait for vf becomes vmcnt(4), leaving K(t+1) stages in flight
        bf16x8 vf[4];
#pragma unroll
        for (int nh = 0; nh < 4; ++nh)
            vf[nh] = *(const bf16x8*)(vtile + (size_t)t * 4096 + nh * 512);
        __builtin_amdgcn_sched_barrier(0);   // pin: vf issued before K stages

        // stage K(t+1) into the other ring half (private, no barrier)
        if (t < 31) {
            const bf16_t* Kt = Kw + (size_t)(t + 1) * 4096;
            char* kb_ = kring + (((t + 1) & 1) << 12);
#pragma unroll
            for (int j = 0; j < 4; ++j)
                gload16(Kt + (size_t)j * 512 + klo, kb_ + j * 1024);
        }

        const bf16_t* k0 = (const bf16_t*)(kring + ((t & 1) << 12));
        bf16x8 kf0[2], kf1[2];
#pragma unroll
        for (int kg = 0; kg < 2; ++kg) {
            const bf16_t* krow = k0 + (kg * 16 + l15) * 64;
            kf0[kg] = *(const bf16x8*)(krow + (quad ^ x7) * 8);
            kf1[kg] = *(const bf16x8*)(krow + ((quad + 4) ^ x7) * 8);
        }

        // QK cluster: S^T[key=wk*32+kg*16+quad*4+r][qrow=wq*32+qb*16+l15]
        f32x4 s_[2][2];
        __builtin_amdgcn_s_setprio(1);
#pragma unroll
        for (int kg = 0; kg < 2; ++kg)
#pragma unroll
            for (int qb = 0; qb < 2; ++qb) {
                s_[kg][qb] = MFMA16x32(kf0[kg], qf[qb][0], fz);
                s_[kg][qb] = MFMA16x32(kf1[kg], qf[qb][1], s_[kg][qb]);
            }
        __builtin_amdgcn_s_setprio(0);

        // exp phase (VALU): p = exp2(s), packed K=32 A-frags (e<4 kg0, e>=4 kg1)
        bf16x8 pf8[2];
#pragma unroll
        for (int qb = 0; qb < 2; ++qb) {
#pragma unroll
            for (int kg = 0; kg < 2; ++kg)
#pragma unroll
                for (int r = 0; r < 4; ++r)
                    pf8[qb][kg * 4 + r] = (bf16_t)fast_exp2(s_[kg][qb][r]);
        }

        // MFMA cluster: lsum + PV (vf k-order matches pf8)
        __builtin_amdgcn_s_setprio(1);
#pragma unroll
        for (int qb = 0; qb < 2; ++qb)
            lacc[qb] = MFMA16x32(pf8[qb], ones8, lacc[qb]);
#pragma unroll
        for (int nh = 0; nh < 4; ++nh)
#pragma unroll
            for (int qb = 0; qb < 2; ++qb)
                o_[qb][nh] = MFMA16x32(pf8[qb], vf[nh], o_[qb][nh]);
        __builtin_amdgcn_s_setprio(0);
        // no __syncthreads: waves drift freely
    }

    // ---- epilogue: drain all waves, then 2-way cross-wave (wk) reduction ----
    __syncthreads();   // all waves done with their K rings (redO/redL overlay)

    if (l15 == 0) {
#pragma unroll
        for (int qb = 0; qb < 2; ++qb)
#pragma unroll
            for (int r = 0; r < 4; ++r)
                redL[w * 32 + qb * 16 + quad * 4 + r] = lacc[qb][r];
    }

    const int cq  = tid >> 2;           // consumer q-row 0..63
    const int cwq = cq >> 5, cql = cq & 31;
    const int chb = (tid & 3) * 8;      // consumer hd base within 32-phase
    const size_t orow = (size_t)b * 2048 + (size_t)qt * 64 + cq;

#pragma unroll
    for (int ph = 0; ph < 2; ++ph) {
        __syncthreads();  // prior phase consumed; redL visible (ph=0)
#pragma unroll
        for (int qb = 0; qb < 2; ++qb)
#pragma unroll
            for (int nj = 0; nj < 2; ++nj) {
                int nh = ph * 2 + nj;
#pragma unroll
                for (int r = 0; r < 4; ++r)
                    redO[w * 1024 + (qb * 16 + quad * 4 + r) * 32 + nj * 16 + l15] =
                        o_[qb][nh][r];
            }
        __syncthreads();  // partials visible

        float lt = redL[cwq * 64 + cql] + redL[cwq * 64 + 32 + cql];
        float linv = 1.f / lt;
        float4 a0 = {0, 0, 0, 0}, a1 = {0, 0, 0, 0};
#pragma unroll
        for (int wk2 = 0; wk2 < 2; ++wk2) {
            const float4* p = (const float4*)(redO + (cwq * 2 + wk2) * 1024 + cql * 32 + chb);
            float4 x = p[0], y = p[1];
            a0.x += x.x; a0.y += x.y; a0.z += x.z; a0.w += x.w;
            a1.x += y.x; a1.y += y.y; a1.z += y.z; a1.w += y.w;
        }
        bf16x8 ov;
        ov[0] = (bf16_t)(a0.x * linv); ov[1] = (bf16_t)(a0.y * linv);
        ov[2] = (bf16_t)(a0.z * linv); ov[3] = (bf16_t)(a0.w * linv);
        ov[4] = (bf16_t)(a1.x * linv); ov[5] = (bf16_t)(a1.y * linv);
        ov[6] = (bf16_t)(a1.z * linv); ov[7] = (bf16_t)(a1.w * linv);
        *(bf16x8*)(Ob + orow * 1024 + h * 64 + ph * 32 + chb) = ov;
    }
}

// ---------------------------------------------------------------------------
extern "C" void kernel_launch(void* const* d_in, const int* in_sizes, int n_in,
                              void* d_out, int out_size, void* d_ws, size_t ws_size,
                              hipStream_t stream) {
    const float* query     = (const float*)d_in[0];
    const float* key_value = (const float*)d_in[1];
    const float* Wq  = (const float*)d_in[2];
    const float* bq  = (const float*)d_in[3];
    const float* Wkv = (const float*)d_in[4];
    const float* bkv = (const float*)d_in[5];
    const float* Wo  = (const float*)d_in[6];
    const float* bo  = (const float*)d_in[7];
    float* out = (float*)d_out;

    char* ws = (char*)d_ws;
    const size_t MB = 1024 * 1024;
    bf16_t* WqT  = (bf16_t*)(ws + 0 * MB);
    bf16_t* WkvT = (bf16_t*)(ws + 2 * MB);
    bf16_t* WoT  = (bf16_t*)(ws + 6 * MB);
    bf16_t* qb   = (bf16_t*)(ws + 8 * MB);
    bf16_t* kvb  = (bf16_t*)(ws + 24 * MB);
    bf16_t* Qp   = (bf16_t*)(ws + 40 * MB);
    bf16_t* Kb   = (bf16_t*)(ws + 56 * MB);
    bf16_t* Vt   = (bf16_t*)(ws + 72 * MB);
    bf16_t* Ob   = (bf16_t*)(ws + 88 * MB);

    prep_kernel<<<9728, 256, 0, stream>>>(query, key_value, Wq, Wkv, Wo,
                                          qb, kvb, WqT, WkvT, WoT);
    gemm_qkv<<<dim3(24, 64), 256, 0, stream>>>(qb, kvb, WqT, WkvT, bq, bkv,
                                               Qp, Kb, Vt);
    attn_kernel<<<2048, 256, 0, stream>>>(Qp, Kb, Vt, Ob);
    gemm_out<<<dim3(8, 64), 256, 0, stream>>>(Ob, WoT, bo, out, 8192, 1024, 1024);
}